// Round 4
// baseline (40.940 us; speedup 1.0000x reference)
//
#include <hip/hip_runtime.h>
#include <hip/hip_bf16.h>

typedef short short8 __attribute__((ext_vector_type(8)));
typedef float f32x4 __attribute__((ext_vector_type(4)));

#define CIN   128
#define COUT  128
#define HH    32
#define WW    32
#define NB    32
#define LTOT  1024
#define KKT   9
#define KDIM  1152

#define WT_OFF   0
#define WT_BYTES (COUT*KDIM*2)            // 294912
#define XT_OFF   WT_BYTES
#define XT_BYTES (NB*HH*WW*CIN*2)         // 8388608

// LDS layout (dynamic): A dbuf 2 x 128rows x 256B = 65536; B tile 6 x 34 x 256B = 52224
#define ABUF  32768
#define BOFF  65536
#define BROW  8704                         // 34 * 256
#define SMEM_BYTES 117760

// ---------------- prep: xt transpose + wt transpose ------------------------
__global__ void prep_kernel(const float* __restrict__ x, const float* __restrict__ w,
                            char* __restrict__ ws) {
  int bid = blockIdx.x;
  if (bid < 1024) {
    // xt[((b*32+h)*32+w)*128 + c] = bf16(x[((b*128+c)*32+h)*32+w])
    __shared__ float tile[CIN][WW + 1];
    int b = bid >> 5, h = bid & 31;
    const float* src = x + ((size_t)b * CIN * HH + h) * WW;
    for (int i = threadIdx.x; i < CIN * WW; i += 256) {
      int c = i >> 5, wv = i & 31;
      tile[c][wv] = src[(size_t)c * HH * WW + wv];
    }
    __syncthreads();
    __hip_bfloat16* dst = (__hip_bfloat16*)(ws + XT_OFF) + (size_t)(b * HH + h) * WW * CIN;
    for (int i = threadIdx.x; i < CIN * WW; i += 256) {
      int wv = i >> 7, c = i & 127;
      dst[wv * CIN + c] = __float2bfloat16(tile[c][wv]);
    }
  } else {
    // wt[o*1152 + kk*128 + c] = bf16(w[(o*128+c)*9 + kk])
    int i = (bid - 1024) * 256 + threadIdx.x;    // covers 147456 exactly (576 blocks)
    int o = i / KDIM;
    int r = i - o * KDIM;
    int kk = r >> 7, c = r & 127;
    ((__hip_bfloat16*)(ws + WT_OFF))[i] = __float2bfloat16(w[(o * CIN + c) * KKT + kk]);
  }
}

// ---------------- conv as implicit GEMM -------------------------------------
__device__ __forceinline__ void gld16(const char* g, char* l) {
  __builtin_amdgcn_global_load_lds(
      (const __attribute__((address_space(1))) void*)g,
      (__attribute__((address_space(3))) void*)l, 16, 0, 0);
}

// 256 blocks x 512 threads. Block tile 128(o) x 128(l), one image-b, 4 h-rows of l.
// B tile: raw xt rows h0-1..h0+4 (zero halo), cols -1..32 (zero cols 0,33), swizzled.
// A: wt streamed over kk (BK=128), double-buffered, global_load_lds, chunk^(row&7).
// 8 waves = 2m x 4n, wave tile 64(o) x 32(l). 9 fat phases of 32 MFMA/wave.
__global__ __launch_bounds__(512, 1)
void conv_mfma_kernel(const char* __restrict__ ws,
                      const float* __restrict__ mask,
                      const float* __restrict__ bias,
                      float* __restrict__ out) {
  extern __shared__ char smem[];
  const int tid = threadIdx.x;
  int bid = blockIdx.x;
  bid = (bid & 7) * 32 + (bid >> 3);     // XCD swizzle, bijective (256 % 8 == 0)
  const int b  = bid >> 3;
  const int l0 = (bid & 7) << 7;         // 128 l per block
  const int h0 = (bid & 7) << 2;         // 4 h-rows per block

  const int lane = tid & 63, wid = tid >> 6;
  const int lr = lane & 15, lg = lane >> 4;
  const int m_base = (wid >> 2) << 6;    // {0,64}
  const int n_base = (wid & 3) << 5;     // {0,32,64,96}

  // ---- mask preload (the ONLY non-staging vmem before the loop) ----
  float mvA[9], mvB[9];
  const float* mrow = mask + l0 + n_base + lr;
#pragma unroll
  for (int kk = 0; kk < 9; ++kk) { mvA[kk] = mrow[kk * LTOT]; mvB[kk] = mrow[kk * LTOT + 16]; }
  asm volatile("s_waitcnt vmcnt(0)" ::: "memory");
#pragma unroll
  for (int kk = 0; kk < 9; ++kk)
    asm volatile("" : "+v"(mvA[kk]), "+v"(mvB[kk]));   // pin: loads may not sink past here

  // ---- zero the B tile (halo stays zero; interior overwritten by gld16) ----
#pragma unroll
  for (int r = 0; r < 7; ++r) {
    int s = r * 512 + tid;
    if (s < 3264) *(f32x4*)(smem + BOFF + s * 16) = (f32x4){0.f, 0.f, 0.f, 0.f};
  }
  asm volatile("s_waitcnt lgkmcnt(0)" ::: "memory");
  __builtin_amdgcn_s_barrier();          // all zeros landed before any gld16 below

  // ---- B interior: 6 rows (block-uniform validity), linear dest, pre-swizzled src ----
  {
    const int col = 1 + (tid >> 4);      // 1..32
    const int ch  = tid & 15;
    const int cs  = ch ^ (col & 7);
    const char* srcb = ws + XT_OFF + ((size_t)b * HH * WW + (col - 1)) * 256 + cs * 16;
#pragma unroll
    for (int r = 0; r < 6; ++r) {
      int hg = h0 - 1 + r;
      if (hg >= 0 && hg < HH)            // block-uniform
        gld16(srcb + (size_t)hg * WW * 256, smem + BOFF + r * BROW + 256 + tid * 16);
    }
  }

  // ---- A staging: 4 gld16 per thread per kk-tile ----
  const int arow = tid >> 4;                       // 0..31 (row base, +32 per round)
  const int acs  = (tid & 15) ^ (arow & 7);        // (r*32) keeps row&7 invariant
  int asrc[4];
#pragma unroll
  for (int r = 0; r < 4; ++r) asrc[r] = (r * 32 + arow) * 2304 + acs * 16;

  auto stageA = [&](int kk) {
    const char* s = ws + WT_OFF + kk * 256;
    char* d = smem + (kk & 1) * ABUF + tid * 16;
#pragma unroll
    for (int r = 0; r < 4; ++r) gld16(s + asrc[r], d + r * 8192);
  };
  stageA(0);
  stageA(1);

  // ---- per-wave B read constants ----
  const int hl0 = n_base >> 5;
  const int hl1 = (n_base + 16) >> 5;
  const int colb0 = (n_base & 31) + lr;            // = lr
  const int colb1 = ((n_base + 16) & 31) + lr;     // = 16 + lr
  const int xA = (lr & 7) << 4;                    // A-read xor key

  f32x4 acc[4][2], par[4][2];
#pragma unroll
  for (int mi = 0; mi < 4; ++mi)
#pragma unroll
    for (int nj = 0; nj < 2; ++nj) {
      acc[mi][nj] = (f32x4){0.f, 0.f, 0.f, 0.f};
      par[mi][nj] = (f32x4){0.f, 0.f, 0.f, 0.f};
    }

#pragma unroll
  for (int kk = 0; kk < 9; ++kk) {
    if (kk < 8) asm volatile("s_waitcnt vmcnt(4)" ::: "memory");  // A(kk) done, A(kk+1) in flight
    else        asm volatile("s_waitcnt vmcnt(0)" ::: "memory");
    __builtin_amdgcn_s_barrier();

    const char* A = smem + (kk & 1) * ABUF;
    const int di = (kk * 11) >> 5;                 // kk/3
    const int dj = kk - 3 * di;
    const int c0 = colb0 + dj, c1 = colb1 + dj;    // 0..33 (halo cols are zeros)
    const char* B0 = smem + BOFF + (hl0 + di) * BROW + c0 * 256;
    const char* B1 = smem + BOFF + (hl1 + di) * BROW + c1 * 256;
    const int x0 = (c0 & 7) << 4, x1 = (c1 & 7) << 4;

    __builtin_amdgcn_s_setprio(1);
#pragma unroll
    for (int ks = 0; ks < 4; ++ks) {
      const int q = (ks * 4 + lg) << 4;
      short8 af0 = *(const short8*)(A + (m_base      + lr) * 256 + (q ^ xA));
      short8 af1 = *(const short8*)(A + (m_base + 16 + lr) * 256 + (q ^ xA));
      short8 af2 = *(const short8*)(A + (m_base + 32 + lr) * 256 + (q ^ xA));
      short8 af3 = *(const short8*)(A + (m_base + 48 + lr) * 256 + (q ^ xA));
      short8 bf0 = *(const short8*)(B0 + (q ^ x0));
      short8 bf1 = *(const short8*)(B1 + (q ^ x1));
      par[0][0] = __builtin_amdgcn_mfma_f32_16x16x32_bf16(af0, bf0, par[0][0], 0, 0, 0);
      par[1][0] = __builtin_amdgcn_mfma_f32_16x16x32_bf16(af1, bf0, par[1][0], 0, 0, 0);
      par[2][0] = __builtin_amdgcn_mfma_f32_16x16x32_bf16(af2, bf0, par[2][0], 0, 0, 0);
      par[3][0] = __builtin_amdgcn_mfma_f32_16x16x32_bf16(af3, bf0, par[3][0], 0, 0, 0);
      par[0][1] = __builtin_amdgcn_mfma_f32_16x16x32_bf16(af0, bf1, par[0][1], 0, 0, 0);
      par[1][1] = __builtin_amdgcn_mfma_f32_16x16x32_bf16(af1, bf1, par[1][1], 0, 0, 0);
      par[2][1] = __builtin_amdgcn_mfma_f32_16x16x32_bf16(af2, bf1, par[2][1], 0, 0, 0);
      par[3][1] = __builtin_amdgcn_mfma_f32_16x16x32_bf16(af3, bf1, par[3][1], 0, 0, 0);
    }
    __builtin_amdgcn_s_setprio(0);

    // mask fold (pure VALU, private regs)
#pragma unroll
    for (int mi = 0; mi < 4; ++mi)
#pragma unroll
      for (int rr = 0; rr < 4; ++rr) {
        acc[mi][0][rr] += mvA[kk] * par[mi][0][rr];  par[mi][0][rr] = 0.f;
        acc[mi][1][rr] += mvB[kk] * par[mi][1][rr];  par[mi][1][rr] = 0.f;
      }

    asm volatile("s_waitcnt lgkmcnt(0)" ::: "memory");  // my buf reads retired
    __builtin_amdgcn_s_barrier();
    if (kk <= 6) stageA(kk + 2);                        // refill the buffer just read
  }

  // ---- epilogue: C/D layout col(l)=lane&15, row(o)=(lane>>4)*4+rr ----
  float* outb = out + ((size_t)b * COUT) * LTOT + l0;
#pragma unroll
  for (int mi = 0; mi < 4; ++mi) {
#pragma unroll
    for (int rr = 0; rr < 4; ++rr) {
      int o = m_base + mi * 16 + lg * 4 + rr;
      float bv = bias[o];
      outb[(size_t)o * LTOT + n_base      + lr] = acc[mi][0][rr] + bv;
      outb[(size_t)o * LTOT + n_base + 16 + lr] = acc[mi][1][rr] + bv;
    }
  }
}

extern "C" void kernel_launch(void* const* d_in, const int* in_sizes, int n_in,
                              void* d_out, int out_size, void* d_ws, size_t ws_size,
                              hipStream_t stream) {
  const float* x    = (const float*)d_in[0];
  const float* mask = (const float*)d_in[1];
  const float* w    = (const float*)d_in[2];
  const float* bias = (const float*)d_in[3];
  float* out = (float*)d_out;
  char* ws = (char*)d_ws;

  (void)hipFuncSetAttribute(reinterpret_cast<const void*>(conv_mfma_kernel),
                            hipFuncAttributeMaxDynamicSharedMemorySize, SMEM_BYTES);

  prep_kernel<<<1600, 256, 0, stream>>>(x, w, ws);
  conv_mfma_kernel<<<256, 512, SMEM_BYTES, stream>>>(ws, mask, bias, out);
}

// Round 5
// 40.460 us; speedup vs baseline: 1.0119x; 1.0119x over previous
//
#include <hip/hip_runtime.h>
#include <hip/hip_bf16.h>

typedef short short8 __attribute__((ext_vector_type(8)));
typedef float f32x4 __attribute__((ext_vector_type(4)));
typedef float f32x16 __attribute__((ext_vector_type(16)));

#define CIN   128
#define COUT  128
#define HH    32
#define WW    32
#define LTOT  1024
#define KKT   9
#define KDIM  1152

#define WT_OFF   0
#define WT_BYTES (COUT*KDIM*2)            // 294912
#define XT_OFF   WT_BYTES
#define XT_BYTES (32*HH*WW*CIN*2)         // 8388608

// LDS: A dbuf 2 x 32KB at [0,65536); B 6 x 32 x 256B = 48KB at [65536, 114688)
// epilogue reuses [0, 65536) as a 128o x 128l f32 tile
#define ABUF  32768
#define BOFF  65536
#define SMEM_BYTES 114688

// ---------------- prep: xt transpose + wt transpose (verified r2-r4) --------
__global__ void prep_kernel(const float* __restrict__ x, const float* __restrict__ w,
                            char* __restrict__ ws) {
  int bid = blockIdx.x;
  if (bid < 1024) {
    __shared__ float tile[CIN][WW + 1];
    int b = bid >> 5, h = bid & 31;
    const float* src = x + ((size_t)b * CIN * HH + h) * WW;
    for (int i = threadIdx.x; i < CIN * WW; i += 256) {
      int c = i >> 5, wv = i & 31;
      tile[c][wv] = src[(size_t)c * HH * WW + wv];
    }
    __syncthreads();
    __hip_bfloat16* dst = (__hip_bfloat16*)(ws + XT_OFF) + (size_t)(b * HH + h) * WW * CIN;
    for (int i = threadIdx.x; i < CIN * WW; i += 256) {
      int wv = i >> 7, c = i & 127;
      dst[wv * CIN + c] = __float2bfloat16(tile[c][wv]);
    }
  } else {
    int i = (bid - 1024) * 256 + threadIdx.x;    // covers 147456 exactly
    int o = i / KDIM;
    int r = i - o * KDIM;
    int kk = r >> 7, c = r & 127;
    ((__hip_bfloat16*)(ws + WT_OFF))[i] = __float2bfloat16(w[(o * CIN + c) * KKT + kk]);
  }
}

__device__ __forceinline__ void gld16(const char* g, char* l) {
  __builtin_amdgcn_global_load_lds(
      (const __attribute__((address_space(1))) void*)g,
      (__attribute__((address_space(3))) void*)l, 16, 0, 0);
}

// 256 blocks x 256 threads (4 waves). Block tile 128(o) x 128(l), one b, 4 h-rows.
// Waves: 2m x 2n, wave tile 64x64 via 2x2 of mfma_f32_32x32x16_bf16.
// LDS[row][slot16B] = global[row][slot ^ (row&7)] for both A and B (T2 swizzle).
// B resident (staged once); A streamed per kk, double-buffered, counted vmcnt.
__global__ __launch_bounds__(256, 1)
void conv_mfma_kernel(const char* __restrict__ ws,
                      const float* __restrict__ mask,
                      const float* __restrict__ bias,
                      float* __restrict__ out) {
  extern __shared__ char smem[];
  const int tid = threadIdx.x;
  int bid = blockIdx.x;
  bid = (bid & 7) * 32 + (bid >> 3);     // XCD swizzle, bijective (256 % 8 == 0)
  const int b  = bid >> 3;
  const int l0 = (bid & 7) << 7;         // 128 l per block
  const int h0 = (bid & 7) << 2;         // 4 h-rows per block

  const int lane = tid & 63, wid = tid >> 6;
  const int ln31 = lane & 31, hi = lane >> 5;
  const int mw = (wid >> 1) << 6;        // wave m base {0,64}
  const int nw = (wid & 1) << 6;         // wave n base {0,64}

  // ---- mask preload (only non-staging vmem before the loop) ----
  float mv0[9], mv1[9];
  {
    const float* mr = mask + l0 + nw + ln31;
#pragma unroll
    for (int kk = 0; kk < 9; ++kk) { mv0[kk] = mr[kk * LTOT]; mv1[kk] = mr[kk * LTOT + 32]; }
  }
  asm volatile("s_waitcnt vmcnt(0)" ::: "memory");
#pragma unroll
  for (int kk = 0; kk < 9; ++kk)
    asm volatile("" : "+v"(mv0[kk]), "+v"(mv1[kk]));

  // ---- staging constants: chunk q = r*256+tid -> row q>>4, ch q&15 ----
  const int t4 = tid >> 4, ch = tid & 15;
  const int xkey = t4 & 7;                       // == row&7 for all r-slices
  const int cx = (ch ^ xkey) << 4;               // pre-swizzled source chunk byte

  // ---- B stage, once: rows h0-1..h0+4 (zero-fill OOB rows), 32 cols ----
  {
#pragma unroll
    for (int r = 0; r < 12; ++r) {
      const int hrow = r >> 1;
      const int hg = h0 - 1 + hrow;
      const int col = ((r & 1) << 4) + t4;       // 0..31, col&7 == xkey
      char* dst = smem + BOFF + r * 4096 + tid * 16;
      if ((unsigned)hg < (unsigned)HH)           // block-uniform
        gld16(ws + XT_OFF + (size_t)(((b * HH + hg) * WW + col) << 8) + cx, dst);
      else
        *(f32x4*)dst = (f32x4){0.f, 0.f, 0.f, 0.f};
    }
  }

  // ---- A stage: 8 gld16/thread per kk tile ----
  int asrc[8];
#pragma unroll
  for (int r = 0; r < 8; ++r) asrc[r] = (r * 16 + t4) * 2304 + cx;
  auto stageA = [&](int kk) {
    const char* s = ws + WT_OFF + kk * 256;
    char* d = smem + (kk & 1) * ABUF + tid * 16;
#pragma unroll
    for (int r = 0; r < 8; ++r) gld16(s + asrc[r], d + r * 4096);
  };
  stageA(0);
  stageA(1);

  f32x16 acc[2][2], par[2][2];
#pragma unroll
  for (int mi = 0; mi < 2; ++mi)
#pragma unroll
    for (int nj = 0; nj < 2; ++nj)
#pragma unroll
      for (int r = 0; r < 16; ++r) { acc[mi][nj][r] = 0.f; par[mi][nj][r] = 0.f; }

  const int xa = (ln31 & 7);                     // A-read xor key (row&7)
  const char* Ar0 = (const char*)0;

#pragma unroll
  for (int kk = 0; kk < 9; ++kk) {
    if (kk < 8) asm volatile("s_waitcnt vmcnt(8)" ::: "memory");  // A(kk)+B done, A(kk+1) in flight
    else        asm volatile("s_waitcnt vmcnt(0)" ::: "memory");
    __builtin_amdgcn_s_barrier();

    const char* A = smem + (kk & 1) * ABUF;
    const int di = (kk * 11) >> 5;               // kk/3
    const int dj = kk - 3 * di;
    const int colv = ln31 + dj - 1;              // -1..32
    const bool bvalid = (unsigned)colv < (unsigned)WW;
    const int colc = bvalid ? colv : 0;
    const int xb = colc & 7;
    const char* B0 = smem + BOFF + ((nw >> 5) + 0 + di) * 8192 + colc * 256;
    const char* B1 = smem + BOFF + ((nw >> 5) + 1 + di) * 8192 + colc * 256;
    const char* A0 = A + (mw + ln31) * 256;
    const char* A1 = A + (mw + 32 + ln31) * 256;

    __builtin_amdgcn_s_setprio(1);
#pragma unroll
    for (int ks = 0; ks < 8; ++ks) {
      const int sl = ks * 2 + hi;
      short8 a0 = *(const short8*)(A0 + ((sl ^ xa) << 4));
      short8 a1 = *(const short8*)(A1 + ((sl ^ xa) << 4));
      short8 b0 = *(const short8*)(B0 + ((sl ^ xb) << 4));
      short8 b1 = *(const short8*)(B1 + ((sl ^ xb) << 4));
      par[0][0] = __builtin_amdgcn_mfma_f32_32x32x16_bf16(a0, b0, par[0][0], 0, 0, 0);
      par[1][0] = __builtin_amdgcn_mfma_f32_32x32x16_bf16(a1, b0, par[1][0], 0, 0, 0);
      par[0][1] = __builtin_amdgcn_mfma_f32_32x32x16_bf16(a0, b1, par[0][1], 0, 0, 0);
      par[1][1] = __builtin_amdgcn_mfma_f32_32x32x16_bf16(a1, b1, par[1][1], 0, 0, 0);
    }
    __builtin_amdgcn_s_setprio(0);

    // mask fold; OOB column taps contribute 0 (garbage * 0)
    const float m0 = bvalid ? mv0[kk] : 0.f;
    const float m1 = bvalid ? mv1[kk] : 0.f;
#pragma unroll
    for (int mi = 0; mi < 2; ++mi)
#pragma unroll
      for (int r = 0; r < 16; ++r) {
        acc[mi][0][r] += m0 * par[mi][0][r];  par[mi][0][r] = 0.f;
        acc[mi][1][r] += m1 * par[mi][1][r];  par[mi][1][r] = 0.f;
      }

    asm volatile("s_waitcnt lgkmcnt(0)" ::: "memory");
    __builtin_amdgcn_s_barrier();
    if (kk <= 6) stageA(kk + 2);
  }

  // ---- epilogue: acc -> LDS f32 tile [128o][128l] -> full-line stores ----
  // C/D layout (32x32): col(l) = lane&31, row(o) = (r&3) + 8*(r>>2) + 4*hi
  {
    float* ft = (float*)smem;
#pragma unroll
    for (int mi = 0; mi < 2; ++mi)
#pragma unroll
      for (int nj = 0; nj < 2; ++nj) {
        const int lc = nw + nj * 32 + ln31;
#pragma unroll
        for (int r = 0; r < 16; ++r) {
          const int o = mw + mi * 32 + (r & 3) + ((r >> 2) << 3) + (hi << 2);
          ft[o * 128 + lc] = acc[mi][nj][r];
        }
      }
    asm volatile("s_waitcnt lgkmcnt(0)" ::: "memory");
    __builtin_amdgcn_s_barrier();

    const int t5 = tid >> 5, c5 = tid & 31;
    float* outb = out + (size_t)b * COUT * LTOT + l0 + c5 * 4;
#pragma unroll
    for (int oi = 0; oi < 16; ++oi) {
      const int o = oi * 8 + t5;
      f32x4 v = *(const f32x4*)(ft + o * 128 + c5 * 4);
      const float bv = bias[o];
      v.x += bv; v.y += bv; v.z += bv; v.w += bv;
      *(f32x4*)(outb + (size_t)o * LTOT) = v;
    }
  }
  (void)Ar0;
}

extern "C" void kernel_launch(void* const* d_in, const int* in_sizes, int n_in,
                              void* d_out, int out_size, void* d_ws, size_t ws_size,
                              hipStream_t stream) {
  const float* x    = (const float*)d_in[0];
  const float* mask = (const float*)d_in[1];
  const float* w    = (const float*)d_in[2];
  const float* bias = (const float*)d_in[3];
  float* out = (float*)d_out;
  char* ws = (char*)d_ws;

  (void)hipFuncSetAttribute(reinterpret_cast<const void*>(conv_mfma_kernel),
                            hipFuncAttributeMaxDynamicSharedMemorySize, SMEM_BYTES);

  prep_kernel<<<1600, 256, 0, stream>>>(x, w, ws);
  conv_mfma_kernel<<<256, 256, SMEM_BYTES, stream>>>(ws, mask, bias, out);
}

// Round 6
// 39.046 us; speedup vs baseline: 1.0485x; 1.0362x over previous
//
#include <hip/hip_runtime.h>
#include <hip/hip_bf16.h>

typedef short short8 __attribute__((ext_vector_type(8)));
typedef float f32x4 __attribute__((ext_vector_type(4)));

#define CIN   128
#define COUT  128
#define HH    32
#define WW    32
#define LTOT  1024
#define KKT   9
#define KDIM  1152

// LDS: A dbuf 2 x 32KB at [0,65536); B 6 rows x 32 cols x 256B = 48KB at [65536,114688)
#define ABUF  32768
#define BOFF  65536
#define SMEM_BYTES 114688

// ---- tiny prep: wt[o*1152 + kk*128 + c] = bf16(w[(o*128+c)*9 + kk]) ----
__global__ void prep_w_kernel(const float* __restrict__ w, __hip_bfloat16* __restrict__ wt) {
  int i = blockIdx.x * 256 + threadIdx.x;     // 576 blocks -> covers 147456 exactly
  int o = i / KDIM;
  int r = i - o * KDIM;
  int kk = r >> 7, c = r & 127;
  wt[i] = __float2bfloat16(w[(o * CIN + c) * KKT + kk]);
}

__device__ __forceinline__ void gld16(const char* g, char* l) {
  __builtin_amdgcn_global_load_lds(
      (const __attribute__((address_space(1))) void*)g,
      (__attribute__((address_space(3))) void*)l, 16, 0, 0);
}

// 256 blocks x 512 threads (8 waves, 2m x 4n, wave tile 64o x 32l, mfma 16x16x32).
// B tile built IN-KERNEL from raw f32 x (fused transpose+convert), resident all taps.
// A (weights) streamed per tap from wt, double-buffered, gld16 + counted vmcnt.
// LDS chunk swizzle: slot = chunk ^ (row_or_col & 15), both sides consistent.
__global__ __launch_bounds__(512, 1)
void conv_mfma_kernel(const float* __restrict__ x,
                      const __hip_bfloat16* __restrict__ wt,
                      const float* __restrict__ mask,
                      const float* __restrict__ bias,
                      float* __restrict__ out) {
  extern __shared__ char smem[];
  const int tid = threadIdx.x;
  int bid = blockIdx.x;
  bid = (bid & 7) * 32 + (bid >> 3);     // XCD swizzle, bijective (256 % 8 == 0)
  const int b  = bid >> 3;
  const int l0 = (bid & 7) << 7;         // 128 l per block
  const int h0 = (bid & 7) << 2;         // 4 h-rows per block

  const int lane = tid & 63, wid = tid >> 6;
  const int lr = lane & 15, lg = lane >> 4;
  const int m_base = (wid >> 2) << 6;    // {0,64}
  const int n_base = (wid & 3) << 5;     // {0,32,64,96}
  const int hl = n_base >> 5;

  // ---- issue mask loads ----
  float mvA[9], mvB[9];
  {
    const float* mr = mask + l0 + n_base + lr;
#pragma unroll
    for (int kk = 0; kk < 9; ++kk) { mvA[kk] = mr[kk * LTOT]; mvB[kk] = mr[kk * LTOT + 16]; }
  }

  // ---- issue B-build loads: x[b][c][hg][w], coalesced 128B per (c,hg) ----
  const int wv = tid & 31, cg = tid >> 5;          // col (w), 16-B chunk (8 c's)
  char* bdst = smem + BOFF + wv * 256 + (((cg ^ (wv & 15))) << 4);
  const float* xb = x + (size_t)b * CIN * LTOT;
  float fr[6][8];
#pragma unroll
  for (int r = 0; r < 6; ++r) {
    const int hg = h0 - 1 + r;
    if ((unsigned)hg < (unsigned)HH) {             // block-uniform branch
      const float* s = xb + (size_t)cg * 8 * LTOT + hg * WW + wv;
#pragma unroll
      for (int j = 0; j < 8; ++j) fr[r][j] = s[(size_t)j * LTOT];
    }
  }
  asm volatile("s_waitcnt vmcnt(0)" ::: "memory");
#pragma unroll
  for (int kk = 0; kk < 9; ++kk)
    asm volatile("" : "+v"(mvA[kk]), "+v"(mvB[kk]));

  // ---- convert + write B tile (zero OOB rows) ----
#pragma unroll
  for (int r = 0; r < 6; ++r) {
    const int hg = h0 - 1 + r;
    short8 v = (short8){0, 0, 0, 0, 0, 0, 0, 0};
    if ((unsigned)hg < (unsigned)HH) {
#pragma unroll
      for (int j = 0; j < 8; ++j)
        v[j] = (short)__builtin_bit_cast(unsigned short, __float2bfloat16(fr[r][j]));
    }
    *(short8*)(bdst + r * 8192) = v;
  }

  // ---- A staging: 4 gld16/thread per tap tile (32 KB) ----
  const int t4 = tid >> 4, ch = tid & 15;
  const int cx = ((ch ^ (t4 & 15)) << 4);
  int asrc[4];
#pragma unroll
  for (int r = 0; r < 4; ++r) asrc[r] = (r * 32 + t4) * 2304 + cx;
  const char* wtc = (const char*)wt;
  auto stageA = [&](int kk) {
    const char* s = wtc + kk * 256;
    char* d = smem + (kk & 1) * ABUF + tid * 16;
#pragma unroll
    for (int r = 0; r < 4; ++r) gld16(s + asrc[r], d + r * 8192);
  };
  stageA(0);
  stageA(1);
  asm volatile("s_waitcnt lgkmcnt(0)" ::: "memory");   // B writes done (mine)

  f32x4 acc[4][2], par[4][2];
#pragma unroll
  for (int mi = 0; mi < 4; ++mi)
#pragma unroll
    for (int nj = 0; nj < 2; ++nj) {
      acc[mi][nj] = (f32x4){0.f, 0.f, 0.f, 0.f};
      par[mi][nj] = (f32x4){0.f, 0.f, 0.f, 0.f};
    }

#pragma unroll
  for (int kk = 0; kk < 9; ++kk) {
    if (kk < 8) asm volatile("s_waitcnt vmcnt(4)" ::: "memory");  // A(kk) done, A(kk+1) in flight
    else        asm volatile("s_waitcnt vmcnt(0)" ::: "memory");
    __builtin_amdgcn_s_barrier();

    const char* A = smem + (kk & 1) * ABUF;
    const int di = (kk * 11) >> 5;               // kk/3
    const int dj = kk - 3 * di;
    // nj=0: col = lr+dj-1 (OOB iff lr==0,dj==0); nj=1: col = 16+lr+dj-1 (OOB iff lr==15,dj==2)
    const int col0 = lr + dj - 1;
    const int col1 = 16 + lr + dj - 1;
    const bool v0 = (unsigned)col0 < (unsigned)WW;
    const bool v1 = (unsigned)col1 < (unsigned)WW;
    const int cc0 = v0 ? col0 : 0;
    const int cc1 = v1 ? col1 : 0;
    const char* B0 = smem + BOFF + (hl + di) * 8192 + cc0 * 256;
    const char* B1 = smem + BOFF + (hl + di) * 8192 + cc1 * 256;
    const int x0 = cc0 & 15, x1 = cc1 & 15;
    const char* A0 = A + (m_base      + lr) * 256;
    const char* A1 = A + (m_base + 16 + lr) * 256;
    const char* A2 = A + (m_base + 32 + lr) * 256;
    const char* A3 = A + (m_base + 48 + lr) * 256;

    __builtin_amdgcn_s_setprio(1);
#pragma unroll
    for (int ks = 0; ks < 4; ++ks) {
      const int q = ks * 4 + lg;
      short8 af0 = *(const short8*)(A0 + ((q ^ lr) << 4));
      short8 af1 = *(const short8*)(A1 + ((q ^ lr) << 4));
      short8 af2 = *(const short8*)(A2 + ((q ^ lr) << 4));
      short8 af3 = *(const short8*)(A3 + ((q ^ lr) << 4));
      short8 bf0 = *(const short8*)(B0 + ((q ^ x0) << 4));
      short8 bf1 = *(const short8*)(B1 + ((q ^ x1) << 4));
      par[0][0] = __builtin_amdgcn_mfma_f32_16x16x32_bf16(af0, bf0, par[0][0], 0, 0, 0);
      par[1][0] = __builtin_amdgcn_mfma_f32_16x16x32_bf16(af1, bf0, par[1][0], 0, 0, 0);
      par[2][0] = __builtin_amdgcn_mfma_f32_16x16x32_bf16(af2, bf0, par[2][0], 0, 0, 0);
      par[3][0] = __builtin_amdgcn_mfma_f32_16x16x32_bf16(af3, bf0, par[3][0], 0, 0, 0);
      par[0][1] = __builtin_amdgcn_mfma_f32_16x16x32_bf16(af0, bf1, par[0][1], 0, 0, 0);
      par[1][1] = __builtin_amdgcn_mfma_f32_16x16x32_bf16(af1, bf1, par[1][1], 0, 0, 0);
      par[2][1] = __builtin_amdgcn_mfma_f32_16x16x32_bf16(af2, bf1, par[2][1], 0, 0, 0);
      par[3][1] = __builtin_amdgcn_mfma_f32_16x16x32_bf16(af3, bf1, par[3][1], 0, 0, 0);
    }
    __builtin_amdgcn_s_setprio(0);

    // mask fold; OOB column taps contribute 0 (garbage * 0)
    const float m0 = v0 ? mvA[kk] : 0.f;
    const float m1 = v1 ? mvB[kk] : 0.f;
#pragma unroll
    for (int mi = 0; mi < 4; ++mi)
#pragma unroll
      for (int rr = 0; rr < 4; ++rr) {
        acc[mi][0][rr] += m0 * par[mi][0][rr];  par[mi][0][rr] = 0.f;
        acc[mi][1][rr] += m1 * par[mi][1][rr];  par[mi][1][rr] = 0.f;
      }

    asm volatile("s_waitcnt lgkmcnt(0)" ::: "memory");  // my buf reads retired
    __builtin_amdgcn_s_barrier();
    if (kk <= 6) stageA(kk + 2);                        // refill buffer just read
  }

  // ---- epilogue (r4-verified): col(l)=lane&15, row(o)=(lane>>4)*4+rr ----
  float* outb = out + (size_t)b * COUT * LTOT + l0;
#pragma unroll
  for (int mi = 0; mi < 4; ++mi) {
#pragma unroll
    for (int rr = 0; rr < 4; ++rr) {
      int o = m_base + mi * 16 + lg * 4 + rr;
      float bv = bias[o];
      outb[(size_t)o * LTOT + n_base      + lr] = acc[mi][0][rr] + bv;
      outb[(size_t)o * LTOT + n_base + 16 + lr] = acc[mi][1][rr] + bv;
    }
  }
}

extern "C" void kernel_launch(void* const* d_in, const int* in_sizes, int n_in,
                              void* d_out, int out_size, void* d_ws, size_t ws_size,
                              hipStream_t stream) {
  const float* x    = (const float*)d_in[0];
  const float* mask = (const float*)d_in[1];
  const float* w    = (const float*)d_in[2];
  const float* bias = (const float*)d_in[3];
  float* out = (float*)d_out;
  __hip_bfloat16* wt = (__hip_bfloat16*)d_ws;

  (void)hipFuncSetAttribute(reinterpret_cast<const void*>(conv_mfma_kernel),
                            hipFuncAttributeMaxDynamicSharedMemorySize, SMEM_BYTES);

  prep_w_kernel<<<576, 256, 0, stream>>>(w, wt);
  conv_mfma_kernel<<<256, 512, SMEM_BYTES, stream>>>(x, wt, mask, bias, out);
}